// Round 5
// baseline (427.744 us; speedup 1.0000x reference)
//
#include <hip/hip_runtime.h>
#include <stdint.h>

using u16 = unsigned short;
typedef __attribute__((ext_vector_type(8))) short bf16x8;
typedef __attribute__((ext_vector_type(4))) float f32x4;

constexpr int D  = 512;
constexpr int P  = 256;
constexpr int BM = 128;     // rows per block (4 waves x 32 rows)
constexpr int WS = P + 8;   // ushort stride for w/gated buffer (528 B/row)

__device__ __forceinline__ u16 f2bf(float f) {  // RNE float->bf16
  uint32_t u = __builtin_bit_cast(uint32_t, f);
  u += 0x7fffu + ((u >> 16) & 1u);
  return (u16)(u >> 16);
}

// Fragment-major B layouts: element (tile t, step s, lane l, e) at ((s*NT+t)*64+l)*8+e
// where lane l = g*16 + lrow holds B[col = t*16 + lrow][k = s*32 + g*8 + e].
// Every MFMA B-fragment load is 64 lanes x 16B fully contiguous (1KB).

// ---------------- prep kernels ----------------

__global__ void k_gate(const float* __restrict__ gl, const float* __restrict__ traw,
                       float* __restrict__ gate) {
  int l = threadIdx.x;  // 64 threads
  float t = 1.f / (1.f + expf(-traw[0]));
  t = t * (1.f - 0.001f) + 0.001f;
  float v[4];
  float m = -3.4e38f;
  #pragma unroll
  for (int i = 0; i < 4; ++i) { v[i] = gl[l + i * 64] / t; m = fmaxf(m, v[i]); }
  #pragma unroll
  for (int s = 1; s < 64; s <<= 1) m = fmaxf(m, __shfl_xor(m, s));
  float sum = 0.f;
  #pragma unroll
  for (int i = 0; i < 4; ++i) { v[i] = expf(v[i] - m); sum += v[i]; }
  #pragma unroll
  for (int s = 1; s < 64; s <<= 1) sum += __shfl_xor(sum, s);
  #pragma unroll
  for (int i = 0; i < 4; ++i) gate[l + i * 64] = v[i] / sum;
}

// entmax15 over each row k of adj_logits; writes E[k][j]*gate[j] into egF at (col=j, kk=k)
__global__ void k_adj(const float* __restrict__ adj, const float* __restrict__ gate,
                      u16* __restrict__ egF) {
  int k = blockIdx.x, l = threadIdx.x;  // 256 blocks x 64 threads
  float z[4];
  float m = -3.4e38f;
  #pragma unroll
  for (int i = 0; i < 4; ++i) { z[i] = adj[(size_t)k * P + l + i * 64] * 0.5f; m = fmaxf(m, z[i]); }
  #pragma unroll
  for (int s = 1; s < 64; s <<= 1) m = fmaxf(m, __shfl_xor(m, s));
  float lo = m - 1.f, hi = m;
  for (int it = 0; it < 26; ++it) {
    float tau = 0.5f * (lo + hi), s = 0.f;
    #pragma unroll
    for (int i = 0; i < 4; ++i) { float d = z[i] - tau; s += (d > 0.f) ? d * d : 0.f; }
    #pragma unroll
    for (int sh = 1; sh < 64; sh <<= 1) s += __shfl_xor(s, sh);
    if (s >= 1.f) lo = tau; else hi = tau;
  }
  float tau = 0.5f * (lo + hi);
  int ss = k >> 5, g = (k >> 3) & 3, e = k & 7;
  #pragma unroll
  for (int i = 0; i < 4; ++i) {
    int j = l + i * 64;
    float d = z[i] - tau;
    float p = (d > 0.f) ? d * d : 0.f;
    int tt = j >> 4, lr = j & 15;
    egF[(size_t)(((ss * 16 + tt) * 64) + g * 16 + lr) * 8 + e] = f2bf(p * gate[j]);
  }
}

// proto -> pbF (GEMM1 B: col=p, k=d) and ptF (GEMM3 B: col=d, k=p); pnorm[p] = ||proto_p||^2
__global__ void k_proto(const float* __restrict__ proto, u16* __restrict__ pbF,
                        u16* __restrict__ ptF, float* __restrict__ pnorm) {
  int p = blockIdx.x, t = threadIdx.x;  // 256 blocks x 256 threads
  int ttp = p >> 4, lrp = p & 15;                          // p as col (GEMM1)
  // threads 0..63: pbF in 16B chunks (8 consecutive d) + ssq partial
  if (t < 64) {
    int ss = t >> 2, g = t & 3;
    int d0 = ss * 32 + g * 8;
    float4 va = *(const float4*)(proto + (size_t)p * D + d0);
    float4 vb = *(const float4*)(proto + (size_t)p * D + d0 + 4);
    union { u16 h[8]; uint4 q; } pk;
    pk.h[0] = f2bf(va.x); pk.h[1] = f2bf(va.y); pk.h[2] = f2bf(va.z); pk.h[3] = f2bf(va.w);
    pk.h[4] = f2bf(vb.x); pk.h[5] = f2bf(vb.y); pk.h[6] = f2bf(vb.z); pk.h[7] = f2bf(vb.w);
    *(uint4*)&pbF[(size_t)(((ss * 16 + ttp) * 64) + g * 16 + lrp) * 8] = pk.q;
    float s = va.x * va.x + va.y * va.y + va.z * va.z + va.w * va.w
            + vb.x * vb.x + vb.y * vb.y + vb.z * vb.z + vb.w * vb.w;
    #pragma unroll
    for (int sh = 1; sh < 64; sh <<= 1) s += __shfl_xor(s, sh);
    if (t == 0) pnorm[p] = s;
  }
  // all 256 threads: ptF scatter (col=d, k=p), 2 d-values each
  int ssp = (p >> 5) & 7, gp = (p >> 3) & 3, ep = p & 7;   // p as k-index (GEMM3)
  #pragma unroll
  for (int i = 0; i < 2; ++i) {
    int d = t + i * 256;
    float v = proto[(size_t)p * D + d];
    int hf = d >> 8, tt = (d >> 4) & 15, lr = d & 15;
    ptF[(size_t)(((((hf * 8 + ssp) * 16) + tt) * 64) + gp * 16 + lr) * 8 + ep] = f2bf(v);
  }
}

// ---------------- fused main kernel (zero barriers, wave-private LDS stripes) ----------------

__global__ __launch_bounds__(256, 2)
void k_main(const float* __restrict__ x, const u16* __restrict__ pbF,
            const u16* __restrict__ ptF, const u16* __restrict__ egF,
            const float* __restrict__ pnorm,
            float* __restrict__ out_blend, float* __restrict__ out_gated) {
  __shared__ __align__(16) u16 wbuf[BM][WS];   // 67584 B: entmax weights -> gated (bf16)

  int tid  = threadIdx.x;
  int brow = blockIdx.x * BM;

  int l    = tid & 63;
  int wv   = tid >> 6;        // wave id, 4 waves x 32-row stripes
  int r0   = wv * 32;
  int lrow = l & 15;
  int lk   = (l >> 4) * 8;    // k-offset within 32-wide K-step
  int lr4  = (l >> 4) * 4;    // row offset of this lane's acc quadrant

  // prototype norms for this lane's 16 output cols (issued early, L2-resident)
  float pn[16];
  #pragma unroll
  for (int c = 0; c < 16; ++c) pn[c] = pnorm[c * 16 + lrow];

  // ---- GEMM1: dot[128][256] = x_bf16 @ proto^T ; 2 row-tiles share each B frag ----
  f32x4 acc[2][16];
  #pragma unroll
  for (int rt = 0; rt < 2; ++rt)
    #pragma unroll
    for (int c = 0; c < 16; ++c) acc[rt][c] = {0.f, 0.f, 0.f, 0.f};

  const float* xr0 = x + (size_t)(brow + r0 + lrow) * D + lk;
  const float* xr1 = xr0 + 16 * D;
  const u16*   pbB = pbF + (size_t)l * 8;
  float ssq0 = 0.f, ssq1 = 0.f;

  // depth-2 pipeline: A-regs hold step s, B-regs hold step s+1
  float4 A0, A1, A2, A3, B0, B1, B2, B3;
  A0 = *(const float4*)(xr0);      A1 = *(const float4*)(xr0 + 4);
  A2 = *(const float4*)(xr1);      A3 = *(const float4*)(xr1 + 4);
  B0 = *(const float4*)(xr0 + 32); B1 = *(const float4*)(xr0 + 36);
  B2 = *(const float4*)(xr1 + 32); B3 = *(const float4*)(xr1 + 36);

  #pragma unroll 1
  for (int s = 0; s < 16; s += 2) {
    // ---- even sub-step (regs A*, step s) ----
    {
      ssq0 += A0.x*A0.x + A0.y*A0.y + A0.z*A0.z + A0.w*A0.w
            + A1.x*A1.x + A1.y*A1.y + A1.z*A1.z + A1.w*A1.w;
      ssq1 += A2.x*A2.x + A2.y*A2.y + A2.z*A2.z + A2.w*A2.w
            + A3.x*A3.x + A3.y*A3.y + A3.z*A3.z + A3.w*A3.w;
      union { bf16x8 v; uint32_t u[4]; } fa0, fa1;
      fa0.u[0] = (uint32_t)f2bf(A0.x) | ((uint32_t)f2bf(A0.y) << 16);
      fa0.u[1] = (uint32_t)f2bf(A0.z) | ((uint32_t)f2bf(A0.w) << 16);
      fa0.u[2] = (uint32_t)f2bf(A1.x) | ((uint32_t)f2bf(A1.y) << 16);
      fa0.u[3] = (uint32_t)f2bf(A1.z) | ((uint32_t)f2bf(A1.w) << 16);
      fa1.u[0] = (uint32_t)f2bf(A2.x) | ((uint32_t)f2bf(A2.y) << 16);
      fa1.u[1] = (uint32_t)f2bf(A2.z) | ((uint32_t)f2bf(A2.w) << 16);
      fa1.u[2] = (uint32_t)f2bf(A3.x) | ((uint32_t)f2bf(A3.y) << 16);
      fa1.u[3] = (uint32_t)f2bf(A3.z) | ((uint32_t)f2bf(A3.w) << 16);
      if (s + 2 < 16) {  // reload A* for step s+2 (wave-uniform branch)
        A0 = *(const float4*)(xr0 + (s + 2) * 32);
        A1 = *(const float4*)(xr0 + (s + 2) * 32 + 4);
        A2 = *(const float4*)(xr1 + (s + 2) * 32);
        A3 = *(const float4*)(xr1 + (s + 2) * 32 + 4);
      }
      #pragma unroll
      for (int c = 0; c < 16; ++c) {
        bf16x8 b = *(const bf16x8*)(pbB + (size_t)(s * 16 + c) * 512);
        acc[0][c] = __builtin_amdgcn_mfma_f32_16x16x32_bf16(fa0.v, b, acc[0][c], 0, 0, 0);
        acc[1][c] = __builtin_amdgcn_mfma_f32_16x16x32_bf16(fa1.v, b, acc[1][c], 0, 0, 0);
      }
    }
    // ---- odd sub-step (regs B*, step s+1) ----
    {
      ssq0 += B0.x*B0.x + B0.y*B0.y + B0.z*B0.z + B0.w*B0.w
            + B1.x*B1.x + B1.y*B1.y + B1.z*B1.z + B1.w*B1.w;
      ssq1 += B2.x*B2.x + B2.y*B2.y + B2.z*B2.z + B2.w*B2.w
            + B3.x*B3.x + B3.y*B3.y + B3.z*B3.z + B3.w*B3.w;
      union { bf16x8 v; uint32_t u[4]; } fb0, fb1;
      fb0.u[0] = (uint32_t)f2bf(B0.x) | ((uint32_t)f2bf(B0.y) << 16);
      fb0.u[1] = (uint32_t)f2bf(B0.z) | ((uint32_t)f2bf(B0.w) << 16);
      fb0.u[2] = (uint32_t)f2bf(B1.x) | ((uint32_t)f2bf(B1.y) << 16);
      fb0.u[3] = (uint32_t)f2bf(B1.z) | ((uint32_t)f2bf(B1.w) << 16);
      fb1.u[0] = (uint32_t)f2bf(B2.x) | ((uint32_t)f2bf(B2.y) << 16);
      fb1.u[1] = (uint32_t)f2bf(B2.z) | ((uint32_t)f2bf(B2.w) << 16);
      fb1.u[2] = (uint32_t)f2bf(B3.x) | ((uint32_t)f2bf(B3.y) << 16);
      fb1.u[3] = (uint32_t)f2bf(B3.z) | ((uint32_t)f2bf(B3.w) << 16);
      if (s + 3 < 16) {  // reload B* for step s+3
        B0 = *(const float4*)(xr0 + (s + 3) * 32);
        B1 = *(const float4*)(xr0 + (s + 3) * 32 + 4);
        B2 = *(const float4*)(xr1 + (s + 3) * 32);
        B3 = *(const float4*)(xr1 + (s + 3) * 32 + 4);
      }
      #pragma unroll
      for (int c = 0; c < 16; ++c) {
        bf16x8 b = *(const bf16x8*)(pbB + (size_t)((s + 1) * 16 + c) * 512);
        acc[0][c] = __builtin_amdgcn_mfma_f32_16x16x32_bf16(fb0.v, b, acc[0][c], 0, 0, 0);
        acc[1][c] = __builtin_amdgcn_mfma_f32_16x16x32_bf16(fb1.v, b, acc[1][c], 0, 0, 0);
      }
    }
  }

  // full row ssq: union over the 4 lk-groups holding the same row
  ssq0 += __shfl_xor(ssq0, 16); ssq0 += __shfl_xor(ssq0, 32);
  ssq1 += __shfl_xor(ssq1, 16); ssq1 += __shfl_xor(ssq1, 32);
  float xnj[2][4];
  #pragma unroll
  for (int j = 0; j < 4; ++j) {
    xnj[0][j] = __shfl(ssq0, lr4 + j);
    xnj[1][j] = __shfl(ssq1, lr4 + j);
  }

  // ---- z = -0.5*sqrt(clip(xn - 2*dot + pn, 0)) in place ----
  #pragma unroll
  for (int rt = 0; rt < 2; ++rt)
    #pragma unroll
    for (int c = 0; c < 16; ++c)
      #pragma unroll
      for (int j = 0; j < 4; ++j) {
        float sq = xnj[rt][j] - 2.f * acc[rt][c][j] + pn[c];
        acc[rt][c][j] = -0.5f * sqrtf(fmaxf(sq, 0.f));
      }

  // ---- entmax15: bisection fully in registers (8 rows/lane, reduce over 16-lane group) ----
  float mj[2][4] = {{-3.4e38f,-3.4e38f,-3.4e38f,-3.4e38f},{-3.4e38f,-3.4e38f,-3.4e38f,-3.4e38f}};
  #pragma unroll
  for (int rt = 0; rt < 2; ++rt)
    #pragma unroll
    for (int c = 0; c < 16; ++c)
      #pragma unroll
      for (int j = 0; j < 4; ++j) mj[rt][j] = fmaxf(mj[rt][j], acc[rt][c][j]);
  #pragma unroll
  for (int rt = 0; rt < 2; ++rt)
    #pragma unroll
    for (int j = 0; j < 4; ++j) {
      mj[rt][j] = fmaxf(mj[rt][j], __shfl_xor(mj[rt][j], 1));
      mj[rt][j] = fmaxf(mj[rt][j], __shfl_xor(mj[rt][j], 2));
      mj[rt][j] = fmaxf(mj[rt][j], __shfl_xor(mj[rt][j], 4));
      mj[rt][j] = fmaxf(mj[rt][j], __shfl_xor(mj[rt][j], 8));
    }
  float lo[2][4], hi[2][4];
  #pragma unroll
  for (int rt = 0; rt < 2; ++rt)
    #pragma unroll
    for (int j = 0; j < 4; ++j) { lo[rt][j] = mj[rt][j] - 1.f; hi[rt][j] = mj[rt][j]; }

  for (int it = 0; it < 18; ++it) {
    float tau[2][4], s[2][4];
    #pragma unroll
    for (int rt = 0; rt < 2; ++rt)
      #pragma unroll
      for (int j = 0; j < 4; ++j) { tau[rt][j] = 0.5f * (lo[rt][j] + hi[rt][j]); s[rt][j] = 0.f; }
    #pragma unroll
    for (int c = 0; c < 16; ++c)
      #pragma unroll
      for (int rt = 0; rt < 2; ++rt)
        #pragma unroll
        for (int j = 0; j < 4; ++j) {
          float d = fmaxf(acc[rt][c][j] - tau[rt][j], 0.f);
          s[rt][j] = fmaf(d, d, s[rt][j]);
        }
    #pragma unroll
    for (int rt = 0; rt < 2; ++rt)
      #pragma unroll
      for (int j = 0; j < 4; ++j) {
        s[rt][j] += __shfl_xor(s[rt][j], 1);
        s[rt][j] += __shfl_xor(s[rt][j], 2);
        s[rt][j] += __shfl_xor(s[rt][j], 4);
        s[rt][j] += __shfl_xor(s[rt][j], 8);
        bool ge = (s[rt][j] >= 1.f);
        lo[rt][j] = ge ? tau[rt][j] : lo[rt][j];
        hi[rt][j] = ge ? hi[rt][j] : tau[rt][j];
      }
  }

  // ---- weights -> bf16 -> LDS (wave-private stripe; layout transpose for A-frags) ----
  {
    float tau[2][4];
    #pragma unroll
    for (int rt = 0; rt < 2; ++rt)
      #pragma unroll
      for (int j = 0; j < 4; ++j) tau[rt][j] = 0.5f * (lo[rt][j] + hi[rt][j]);
    #pragma unroll
    for (int rt = 0; rt < 2; ++rt)
      #pragma unroll
      for (int c = 0; c < 16; ++c)
        #pragma unroll
        for (int j = 0; j < 4; ++j) {
          float d = fmaxf(acc[rt][c][j] - tau[rt][j], 0.f);
          wbuf[r0 + rt * 16 + lr4 + j][c * 16 + lrow] = f2bf(d * d);
        }
  }

  // ---- GEMM2: routed_g[128][256] = w @ E_g ----
  f32x4 acc2[2][16];
  #pragma unroll
  for (int rt = 0; rt < 2; ++rt)
    #pragma unroll
    for (int c = 0; c < 16; ++c) acc2[rt][c] = {0.f, 0.f, 0.f, 0.f};

  const u16* egB = egF + (size_t)l * 8;
  #pragma unroll 1
  for (int s = 0; s < 8; ++s) {
    bf16x8 a0 = *(const bf16x8*)&wbuf[r0 + lrow][s * 32 + lk];
    bf16x8 a1 = *(const bf16x8*)&wbuf[r0 + 16 + lrow][s * 32 + lk];
    #pragma unroll
    for (int c = 0; c < 16; ++c) {
      bf16x8 b = *(const bf16x8*)(egB + (size_t)(s * 16 + c) * 512);
      acc2[0][c] = __builtin_amdgcn_mfma_f32_16x16x32_bf16(a0, b, acc2[0][c], 0, 0, 0);
      acc2[1][c] = __builtin_amdgcn_mfma_f32_16x16x32_bf16(a1, b, acc2[1][c], 0, 0, 0);
    }
  }

  // ---- row-normalize: gated = routed_g / (rowsum + 1e-8) ----
  float part[2][4] = {{0.f,0.f,0.f,0.f},{0.f,0.f,0.f,0.f}};
  #pragma unroll
  for (int rt = 0; rt < 2; ++rt)
    #pragma unroll
    for (int c = 0; c < 16; ++c)
      #pragma unroll
      for (int j = 0; j < 4; ++j) part[rt][j] += acc2[rt][c][j];
  #pragma unroll
  for (int rt = 0; rt < 2; ++rt)
    #pragma unroll
    for (int j = 0; j < 4; ++j) {
      part[rt][j] += __shfl_xor(part[rt][j], 1);
      part[rt][j] += __shfl_xor(part[rt][j], 2);
      part[rt][j] += __shfl_xor(part[rt][j], 4);
      part[rt][j] += __shfl_xor(part[rt][j], 8);
      part[rt][j] = 1.f / (part[rt][j] + 1e-8f);
    }

  #pragma unroll
  for (int rt = 0; rt < 2; ++rt)
    #pragma unroll
    for (int c = 0; c < 16; ++c) {
      int col = c * 16 + lrow;
      #pragma unroll
      for (int j = 0; j < 4; ++j) {
        int row = r0 + rt * 16 + lr4 + j;
        float g = acc2[rt][c][j] * part[rt][j];
        out_gated[(size_t)(brow + row) * P + col] = g;
        wbuf[row][col] = f2bf(g);   // same wave-private stripe; w is dead
      }
    }

  // ---- GEMM3: blended[128][512] = gated @ proto (two 256-col halves) ----
  #pragma unroll 1
  for (int half = 0; half < 2; ++half) {
    f32x4 acc3[2][16];
    #pragma unroll
    for (int rt = 0; rt < 2; ++rt)
      #pragma unroll
      for (int c = 0; c < 16; ++c) acc3[rt][c] = {0.f, 0.f, 0.f, 0.f};
    const u16* ptB = ptF + (size_t)half * 8 * 16 * 512 + (size_t)l * 8;
    #pragma unroll 1
    for (int s = 0; s < 8; ++s) {
      bf16x8 a0 = *(const bf16x8*)&wbuf[r0 + lrow][s * 32 + lk];
      bf16x8 a1 = *(const bf16x8*)&wbuf[r0 + 16 + lrow][s * 32 + lk];
      #pragma unroll
      for (int c = 0; c < 16; ++c) {
        bf16x8 b = *(const bf16x8*)(ptB + (size_t)(s * 16 + c) * 512);
        acc3[0][c] = __builtin_amdgcn_mfma_f32_16x16x32_bf16(a0, b, acc3[0][c], 0, 0, 0);
        acc3[1][c] = __builtin_amdgcn_mfma_f32_16x16x32_bf16(a1, b, acc3[1][c], 0, 0, 0);
      }
    }
    #pragma unroll
    for (int rt = 0; rt < 2; ++rt)
      #pragma unroll
      for (int c = 0; c < 16; ++c) {
        int dcol = half * 256 + c * 16 + lrow;
        #pragma unroll
        for (int j = 0; j < 4; ++j) {
          int row = r0 + rt * 16 + lr4 + j;
          out_blend[(size_t)(brow + row) * D + dcol] = acc3[rt][c][j];
        }
      }
  }
}

// ---------------- launcher ----------------

extern "C" void kernel_launch(void* const* d_in, const int* in_sizes, int n_in,
                              void* d_out, int out_size, void* d_ws, size_t ws_size,
                              hipStream_t stream) {
  const float* x     = (const float*)d_in[0];
  const float* proto = (const float*)d_in[1];
  const float* adj   = (const float*)d_in[2];
  const float* gl    = (const float*)d_in[3];
  const float* traw  = (const float*)d_in[4];
  int N = in_sizes[0] / D;  // 65536

  u16*   pbF   = (u16*)d_ws;                  // [16][16][64][8] bf16  GEMM1 B (256 KB)
  u16*   ptF   = pbF + (size_t)P * D;         // [2][8][16][64][8]     GEMM3 B (256 KB)
  u16*   egF   = ptF + (size_t)D * P;         // [8][16][64][8]        GEMM2 B (128 KB)
  float* pnorm = (float*)(egF + (size_t)P * P);
  float* gate  = pnorm + P;

  float* out_blend = (float*)d_out;
  float* out_gated = out_blend + (size_t)N * D;

  k_gate<<<1, 64, 0, stream>>>(gl, traw, gate);
  k_proto<<<P, 256, 0, stream>>>(proto, pbF, ptF, pnorm);
  k_adj<<<P, 64, 0, stream>>>(adj, gate, egF);
  k_main<<<N / BM, 256, 0, stream>>>(x, pbF, ptF, egF, pnorm, out_blend, out_gated);
}